// Round 6
// baseline (378.406 us; speedup 1.0000x reference)
//
#include <hip/hip_runtime.h>
#include <hip/hip_bf16.h>
#include <math.h>

#define NNODES 50000
#define NEDGES 800000
#define NGRAPH 64
#define FIN 128
#define HC 256     // H * HID
#define NHEAD 4
#define NOUT 10
#define ETOT (NEDGES + NNODES)   // edges + self-loops
#define NB196 ((NNODES + 255) / 256)   // 196 sort buckets
#define BCAP 5376                       // per-bucket capacity (15 sigma above mean 4337)
#define S1CHUNK 4096                    // edges per scatter1 block (16/thread)
#define NBS1 ((ETOT + S1CHUNK - 1) / S1CHUNK)   // 208

// Channel permutation σ (within each 64-channel head block):
//   stored p = (c & ~63) | ((c&15)<<2) | ((c>>4)&3)   [actual c -> stored p]
// Hb (fp8) and Ab (bf16) live in σ-layout; w2b/w3b K-dims σ-permuted at
// conversion; bias/Wl loads re-indexed; es/ed epilogue uses fp32 acc directly.

typedef unsigned short u16;
typedef unsigned char u8;
typedef __attribute__((ext_vector_type(8))) short short8;
typedef __attribute__((ext_vector_type(4))) float f32x4;
typedef __attribute__((ext_vector_type(2))) float f32x2;

__device__ inline u16 f2b(float f) {
    union { float f; unsigned u; } v; v.f = f;
    unsigned r = v.u + 0x7FFF + ((v.u >> 16) & 1);   // RNE (finite values)
    return (u16)(r >> 16);
}
__device__ inline float b2f(u16 u) {
    union { unsigned u; float f; } v; v.u = ((unsigned)u) << 16; return v.f;
}

__device__ inline void gload_lds16(const void* g, void* l) {
    __builtin_amdgcn_global_load_lds(
        (const __attribute__((address_space(1))) unsigned*)g,
        (__attribute__((address_space(3))) unsigned*)l, 16, 0, 0);
}

// ---------------- prep: bf16 conversions only ----------------

#define CS0 (NNODES * FIN)   // 6,400,000
#define CS1 (HC * FIN)       // 32,768
#define CS2 (HC * HC)        // 65,536
#define NBCONV (((CS0 + CS1 + 2 * CS2) / 4 + 255) / 256)   // 6410

__global__ void prep_kernel(const float* __restrict__ x, const float* __restrict__ W1,
                            const float* __restrict__ W2, const float* __restrict__ W3,
                            u16* __restrict__ xb, u16* __restrict__ w1b,
                            u16* __restrict__ w2b, u16* __restrict__ w3b) {
    int b = blockIdx.x;
    long i = (long)(b * 256 + threadIdx.x) * 4;
    if (i < CS0) {
        float4 v = *(const float4*)(x + i);
        ushort4 o;
        o.x = f2b(v.x); o.y = f2b(v.y); o.z = f2b(v.z); o.w = f2b(v.w);
        *(ushort4*)(xb + i) = o;
    } else if (i < CS0 + CS1) {
        long off = i - CS0;
        float4 v = *(const float4*)(W1 + off);
        ushort4 o;
        o.x = f2b(v.x); o.y = f2b(v.y); o.z = f2b(v.z); o.w = f2b(v.w);
        *(ushort4*)(w1b + off) = o;
    } else if (i < CS0 + CS1 + 2 * CS2) {
        const float* src; u16* dst; long off;
        if (i < CS0 + CS1 + CS2) { src = W2; dst = w2b; off = i - CS0 - CS1; }
        else                     { src = W3; dst = w3b; off = i - CS0 - CS1 - CS2; }
        float4 v = *(const float4*)(src + off);
        int row = (int)(off >> 8), col = (int)(off & 255);
        float vv[4] = {v.x, v.y, v.z, v.w};
        #pragma unroll
        for (int k = 0; k < 4; ++k) {
            int c = col + k;
            int pp = (c & ~63) | ((c & 15) << 2) | ((c >> 4) & 3);
            dst[row * 256 + pp] = f2b(vv[k]);
        }
    }
}

// ---------------- edge sort pass 1: block-aggregated atomics into fixed- ----
// capacity bucket slots (no prescan needed). Packed u32: src | local-dst<<16.

__global__ __launch_bounds__(256) void scatter1_kernel(const int* __restrict__ ei,
                                                       int* __restrict__ bcur,
                                                       unsigned* __restrict__ tmp) {
    __shared__ int hist[NB196];
    __shared__ int basec[NB196];
    int tid = threadIdx.x;
    int e0 = blockIdx.x * S1CHUNK;
    for (int i = tid; i < NB196; i += 256) hist[i] = 0;
    __syncthreads();
    int bkt[16], rnk[16];
    unsigned pk[16];
    #pragma unroll
    for (int k = 0; k < 16; ++k) {
        int e = e0 + k * 256 + tid;
        bkt[k] = -1;
        if (e < ETOT) {
            int src, dstn;
            if (e < NEDGES) { src = ei[e]; dstn = ei[NEDGES + e]; }
            else            { src = dstn = e - NEDGES; }
            int b = dstn >> 8;
            bkt[k] = b;
            rnk[k] = atomicAdd(&hist[b], 1);
            pk[k] = (unsigned)src | ((unsigned)(dstn & 255) << 16);
        }
    }
    __syncthreads();
    for (int i = tid; i < NB196; i += 256) {
        int h = hist[i];
        basec[i] = h ? atomicAdd(&bcur[i], h) : 0;
    }
    __syncthreads();
    #pragma unroll
    for (int k = 0; k < 16; ++k) {
        if (bkt[k] >= 0) {
            int pos = basec[bkt[k]] + rnk[k];
            if (pos < BCAP)
                tmp[(size_t)bkt[k] * BCAP + pos] = pk[k];
        }
    }
}

// ---------------- bucket-total scan (196 values, 1 block) + graph offsets ----

__global__ __launch_bounds__(256) void scanb_kernel(const int* __restrict__ bcur,
                                                    int* __restrict__ bsum,
                                                    const int* __restrict__ batch,
                                                    int* __restrict__ goff) {
    int tid = threadIdx.x, lane = tid & 63, wid = tid >> 6;
    __shared__ int ws[4];
    int v = 0;
    if (tid < NB196) { v = bcur[tid]; if (v > BCAP) v = BCAP; }
    int x = v;
    #pragma unroll
    for (int o = 1; o < 64; o <<= 1) {
        int t = __shfl_up(x, o);
        if (lane >= o) x += t;
    }
    if (lane == 63) ws[wid] = x;
    __syncthreads();
    if (tid < 4) {
        int w = ws[tid];
        #pragma unroll
        for (int o = 1; o < 4; o <<= 1) {
            int t = __shfl_up(w, o, 4);
            if ((tid & 3) >= o) w += t;
        }
        ws[tid] = w;
    }
    __syncthreads();
    int wexcl = wid ? ws[wid - 1] : 0;
    if (tid <= NB196) bsum[tid] = x - v + wexcl;
    if (tid <= NGRAPH) {
        int g = tid, lo = 0, hi = NNODES;
        while (lo < hi) {
            int mid = (lo + hi) >> 1;
            if (batch[mid] < g) lo = mid + 1; else hi = mid;
        }
        goff[g] = lo;
    }
}

// ---------------- pass 2: stage bucket in LDS, count per-dst, block-scan ----
// -> off[], rank+scatter in LDS, copy out coalesced.

__global__ __launch_bounds__(256) void scatter2_kernel(const unsigned* __restrict__ tmp,
                                                       const int* __restrict__ bcur,
                                                       const int* __restrict__ bsum,
                                                       int* __restrict__ off,
                                                       int* __restrict__ ssrc) {
    __shared__ unsigned ebuf[BCAP];
    __shared__ int ldss[BCAP];
    __shared__ int cnt[256];
    __shared__ int loff[256];
    __shared__ int ws[4];
    int b = blockIdx.x;
    int tid = threadIdx.x;
    int n = bcur[b];
    if (n > BCAP) n = BCAP;
    cnt[tid] = 0;
    const unsigned* tb = tmp + (size_t)b * BCAP;
    for (int i = tid; i < n; i += 256) ebuf[i] = tb[i];
    __syncthreads();
    for (int i = tid; i < n; i += 256) atomicAdd(&cnt[ebuf[i] >> 16], 1);
    __syncthreads();
    // block exclusive scan of cnt[256]
    int lane = tid & 63, wid = tid >> 6;
    int v = cnt[tid];
    int x = v;
    #pragma unroll
    for (int o = 1; o < 64; o <<= 1) {
        int t = __shfl_up(x, o);
        if (lane >= o) x += t;
    }
    if (lane == 63) ws[wid] = x;
    __syncthreads();
    if (tid < 4) {
        int w = ws[tid];
        #pragma unroll
        for (int o = 1; o < 4; o <<= 1) {
            int t = __shfl_up(w, o, 4);
            if ((tid & 3) >= o) w += t;
        }
        ws[tid] = w;
    }
    __syncthreads();
    int wexcl = wid ? ws[wid - 1] : 0;
    int excl = x - v + wexcl;
    loff[tid] = excl;
    off[b * 256 + tid] = excl;
    cnt[tid] = 0;
    __syncthreads();
    for (int i = tid; i < n; i += 256) {
        unsigned pk = ebuf[i];
        int ld = (int)(pk >> 16);
        int rank = atomicAdd(&cnt[ld], 1);
        ldss[loff[ld] + rank] = (int)(pk & 0xFFFFu);
    }
    __syncthreads();
    int s = bsum[b];
    for (int i = tid; i < n; i += 256) ssrc[s + i] = ldss[i];
}

// ---------------- bf16 MFMA GEMM + fused e_src/e_dst epilogue ----------------

#define TBM 128
#define TBN 128
#define TBK 32

__global__ __launch_bounds__(256) void gemm_mfma(const u16* __restrict__ A,
                                                 const u16* __restrict__ B,
                                                 u8* __restrict__ C, int K,
                                                 const float* __restrict__ asrc,
                                                 const float* __restrict__ adst,
                                                 float* __restrict__ es,
                                                 float* __restrict__ ed) {
    __shared__ u16 Als[TBM * TBK];   // 8 KB
    __shared__ u16 Bls[TBN * TBK];   // 8 KB
    int tid = threadIdx.x;
    int wave = tid >> 6, lane = tid & 63;
    int brow = blockIdx.x * TBM, bcol = blockIdx.y * TBN;
    int m_base = (wave >> 1) * 64, n_base = (wave & 1) * 64;
    int r0 = tid >> 2, kc = (tid & 3) * 8;
    int lquad = lane >> 4, l16 = lane & 15;

    f32x4 acc[4][4] = {};

    const u16* ga0 = A + (size_t)(brow + r0) * K + kc;
    const u16* ga1 = A + (size_t)(brow + 64 + r0) * K + kc;
    const u16* gb0 = B + (size_t)(bcol + r0) * K + kc;
    const u16* gb1 = B + (size_t)(bcol + 64 + r0) * K + kc;
    u16* la0 = &Als[r0 * TBK + kc];          // byte offset == tid*16 (wave-contiguous)
    u16* la1 = &Als[(64 + r0) * TBK + kc];
    u16* lb0 = &Bls[r0 * TBK + kc];
    u16* lb1 = &Bls[(64 + r0) * TBK + kc];

    for (int k0 = 0; k0 < K; k0 += TBK) {
        __syncthreads();
        gload_lds16(ga0 + k0, la0);
        gload_lds16(ga1 + k0, la1);
        gload_lds16(gb0 + k0, lb0);
        gload_lds16(gb1 + k0, lb1);
        __syncthreads();
        short8 fa[4], fb[4];
        #pragma unroll
        for (int i = 0; i < 4; ++i) {
            fa[i] = *(const short8*)(&Als[(m_base + i * 16 + l16) * TBK + lquad * 8]);
            fb[i] = *(const short8*)(&Bls[(n_base + i * 16 + l16) * TBK + lquad * 8]);
        }
        #pragma unroll
        for (int i = 0; i < 4; ++i)
            #pragma unroll
            for (int j = 0; j < 4; ++j)
                acc[i][j] = __builtin_amdgcn_mfma_f32_16x16x32_bf16(fa[i], fb[j], acc[i][j], 0, 0, 0);
    }

    // fp8 σ-layout C store: stored bytes n_base+l16*4+{0..3} = acc[i][0..3][r]
    #pragma unroll
    for (int i = 0; i < 4; ++i) {
        int rbase = brow + m_base + i * 16 + lquad * 4;
        #pragma unroll
        for (int r = 0; r < 4; ++r) {
            int row = rbase + r;
            if (row < NNODES) {
                int u = 0;
                u = __builtin_amdgcn_cvt_pk_fp8_f32(acc[i][0][r], acc[i][1][r], u, false);
                u = __builtin_amdgcn_cvt_pk_fp8_f32(acc[i][2][r], acc[i][3][r], u, true);
                *(int*)(C + (size_t)row * HC + bcol + n_base + l16 * 4) = u;
            }
        }
    }

    // fused attention-scalar epilogue (fp32 accumulators — full precision)
    int head = (bcol + n_base) >> 6;
    float asv[4], adv[4];
    #pragma unroll
    for (int j = 0; j < 4; ++j) {
        asv[j] = asrc[head * 64 + j * 16 + l16];
        adv[j] = adst[head * 64 + j * 16 + l16];
    }
    #pragma unroll
    for (int i = 0; i < 4; ++i) {
        #pragma unroll
        for (int r = 0; r < 4; ++r) {
            float ps = 0.f, pd = 0.f;
            #pragma unroll
            for (int j = 0; j < 4; ++j) {
                ps = fmaf(acc[i][j][r], asv[j], ps);
                pd = fmaf(acc[i][j][r], adv[j], pd);
            }
            #pragma unroll
            for (int o = 1; o < 16; o <<= 1) {
                ps += __shfl_xor(ps, o);
                pd += __shfl_xor(pd, o);
            }
            int row = brow + m_base + i * 16 + lquad * 4 + r;
            if (l16 == 0 && row < NNODES) {
                es[row * 4 + head] = ps;
                ed[row * 4 + head] = pd;
            }
        }
    }
}

// ---------------- aggregate: R2 scalar pipeline (1 wave per dst, 4 dst/block, ----
// prologue + 2-deep ssrc prefetch + dbuf slots) with a dwordx2 gather loop:
// 32 lanes x 8B cover one 256B h row -> 2 edges per issue round, 8 rounds per
// 16-edge chunk. ~28% fewer gather-phase instructions (issue-bound per R5
// post-mortem), same bytes, same 64B transactions. 8 f32 acc/lane; halves
// combine via shfl_xor(32); half-0 lanes store 16B.

__global__ __launch_bounds__(256) void aggregate_kernel(const u8* __restrict__ h,
                                                        const int* __restrict__ ssrc,
                                                        const int* __restrict__ off,
                                                        const int* __restrict__ bsum,
                                                        const float* __restrict__ es,
                                                        const float* __restrict__ ed,
                                                        const float* __restrict__ bias,
                                                        u16* __restrict__ out,
                                                        int apply_elu) {
    __shared__ int2 xch[4][4][2][17];   // [wave][head][buf][16 slots + pad]
    const uint2* h64 = (const uint2*)h;   // 32 uint2 per 256B row (σ-layout)
    int wid = threadIdx.x >> 6;
    int dst = blockIdx.x * 4 + wid;
    int lane = threadIdx.x & 63;
    int head = lane >> 4;       // producer (scalar-phase) head
    int j16 = lane & 15;        // producer edge slot
    int half = lane >> 5;       // gather: which of 2 edges per round
    int l32 = lane & 31;        // gather: uint2 index within row
    int ghead = l32 >> 3;       // gather head (stored bytes l32*8 -> head l32>>3)
    int s = off[dst] + bsum[dst >> 8];
    int e = off[dst + 1] + bsum[(dst + 1) >> 8];
    float edh = ed[dst * 4 + head];

    f32x2 acc0 = {0.f, 0.f}, acc1 = {0.f, 0.f}, acc2 = {0.f, 0.f}, acc3 = {0.f, 0.f};
    float dpriv = 0.f;

    // prologue: chunk 0 scalars (every dst has >=1 edge: self-loop)
    {
        int cnt0 = e - s; if (cnt0 > 16) cnt0 = 16;
        int idx0 = s + j16; if (idx0 >= ETOT) idx0 = 0;
        int src0 = ssrc[idx0];
        float l = es[(unsigned)src0 * 4 + head] + edh;
        l = fmaxf(l, 0.2f * l);
        float ex0 = 0.f;
        if (j16 < cnt0) { ex0 = __expf(l); dpriv += ex0; }
        xch[wid][head][0][j16] = make_int2(src0, __float_as_int(ex0));
    }
    // prefetch chunk-1 ssrc into register
    int nidx = s + 16 + j16; if (nidx >= ETOT) nidx = 0;
    int nsrc = ssrc[nidx];

    int buf = 0;
    for (int base = s; base < e; base += 16) {
        int cur = e - base; if (cur > 16) cur = 16;
        int nbase = base + 16;
        // issue next-chunk es gather (nsrc already resident) + t+2 ssrc load
        float esv = es[(unsigned)nsrc * 4 + head];
        int n2idx = base + 32 + j16; if (n2idx >= ETOT) n2idx = 0;
        int n2src = ssrc[n2idx];
        // gather current chunk: 2 edges per round (32 lanes x 8B each)
        const int2* slotg = &xch[wid][ghead][buf][0];
        int rounds = (cur + 1) >> 1;
        for (int r = 0; r < rounds; ++r) {
            int2 pr = slotg[r * 2 + half];      // broadcast among 8 lanes
            float exj = __int_as_float(pr.y);   // staged ex==0 beyond cnt (safe)
            uint2 hv = h64[(size_t)((unsigned)pr.x) * 32 + l32];
            f32x2 e2 = {exj, exj};
            f32x2 lo0 = __builtin_amdgcn_cvt_pk_f32_fp8(hv.x, false);
            f32x2 hi0 = __builtin_amdgcn_cvt_pk_f32_fp8(hv.x, true);
            f32x2 lo1 = __builtin_amdgcn_cvt_pk_f32_fp8(hv.y, false);
            f32x2 hi1 = __builtin_amdgcn_cvt_pk_f32_fp8(hv.y, true);
            acc0 += lo0 * e2;
            acc1 += hi0 * e2;
            acc2 += lo1 * e2;
            acc3 += hi1 * e2;
        }
        // finish next-chunk scalars: exp + slot write (values already landed)
        if (nbase < e) {
            int ncnt = e - nbase; if (ncnt > 16) ncnt = 16;
            float l = esv + edh;
            l = fmaxf(l, 0.2f * l);
            float nex = 0.f;
            if (j16 < ncnt) { nex = __expf(l); dpriv += nex; }
            xch[wid][head][buf ^ 1][j16] = make_int2(nsrc, __float_as_int(nex));
        }
        nsrc = n2src;
        buf ^= 1;
    }

    // denom: sum dpriv across the 16 lanes of this (producer) head group
    #pragma unroll
    for (int o = 1; o < 16; o <<= 1) dpriv += __shfl_xor(dpriv, o);
    float inv = 1.f / (dpriv + 1e-16f);
    // broadcast the gather-head's inv to this lane
    float invg = __shfl(inv, ghead << 4);

    // combine the two edge-halves: lane l and l^32 hold the same channels
    acc0.x += __shfl_xor(acc0.x, 32); acc0.y += __shfl_xor(acc0.y, 32);
    acc1.x += __shfl_xor(acc1.x, 32); acc1.y += __shfl_xor(acc1.y, 32);
    acc2.x += __shfl_xor(acc2.x, 32); acc2.y += __shfl_xor(acc2.y, 32);
    acc3.x += __shfl_xor(acc3.x, 32); acc3.y += __shfl_xor(acc3.y, 32);

    if (half == 0) {
        // 8 channels: stored u16 positions p = l32*8 + k (k=0..7)
        // actual c = ghead*64 + ((sp&3)<<4) + (sp>>2), sp = (l32&7)*8 + k
        float av[8] = {acc0.x, acc0.y, acc1.x, acc1.y, acc2.x, acc2.y, acc3.x, acc3.y};
        short8 ov;
        #pragma unroll
        for (int k = 0; k < 8; ++k) {
            int sp = ((l32 & 7) << 3) | k;
            int c = (ghead << 6) | ((sp & 3) << 4) | (sp >> 2);
            float v = av[k] * invg + bias[c];
            if (apply_elu) v = v > 0.f ? v : __expf(v) - 1.f;
            ov[k] = (short)f2b(v);
        }
        *(short8*)(out + (size_t)dst * HC + l32 * 8) = ov;
    }
}

// ---------------- sliced mean-pool partials: block = (graph, 8 node-slices) ----------------

__global__ __launch_bounds__(256) void pool_kernel(const u16* __restrict__ hin,
                                                   const int* __restrict__ goff,
                                                   float* __restrict__ pp) {
    int g = blockIdx.x;
    int slice = blockIdx.y;            // 0..7
    int lane = threadIdx.x & 63;
    int wid = threadIdx.x >> 6;
    int s = goff[g], e = goff[g + 1];
    float a0 = 0.f, a1 = 0.f, a2 = 0.f, a3 = 0.f;
    for (int n = s + slice * 4 + wid; n < e; n += 32) {
        ushort4 hv = *(const ushort4*)(hin + (size_t)n * HC + lane * 4);
        a0 += b2f(hv.x); a1 += b2f(hv.y); a2 += b2f(hv.z); a3 += b2f(hv.w);
    }
    __shared__ float4 part[4][64];
    part[wid][lane] = make_float4(a0, a1, a2, a3);
    __syncthreads();
    if (wid == 0) {
        float4 p0 = part[0][lane], p1 = part[1][lane], p2 = part[2][lane], p3 = part[3][lane];
        float4 v = make_float4((p0.x + p1.x) + (p2.x + p3.x),
                               (p0.y + p1.y) + (p2.y + p3.y),
                               (p0.z + p1.z) + (p2.z + p3.z),
                               (p0.w + p1.w) + (p2.w + p3.w));
        *(float4*)(pp + ((size_t)(g * 8 + slice)) * HC + lane * 4) = v;
    }
}

// ---------------- final classifier: sum 8 slice-partials, mean, Wl dot ----------------

__global__ __launch_bounds__(64) void final_kernel(const float* __restrict__ pp,
                                                   const int* __restrict__ goff,
                                                   const float* __restrict__ Wl,
                                                   const float* __restrict__ bl,
                                                   float* __restrict__ out) {
    int g = blockIdx.x;
    int lane = threadIdx.x;
    float4 pv = make_float4(0.f, 0.f, 0.f, 0.f);
    #pragma unroll
    for (int sl = 0; sl < 8; ++sl) {
        float4 v = *(const float4*)(pp + ((size_t)(g * 8 + sl)) * HC + lane * 4);
        pv.x += v.x; pv.y += v.y; pv.z += v.z; pv.w += v.w;
    }
    float cntf = fmaxf((float)(goff[g + 1] - goff[g]), 1.f);
    float inv = 1.f / cntf;
    pv.x *= inv; pv.y *= inv; pv.z *= inv; pv.w *= inv;
    int wbase = ((lane >> 4) << 6) | (lane & 15);             // actual ch = wbase+{0,16,32,48}
    float acc[NOUT];
    #pragma unroll
    for (int o = 0; o < NOUT; ++o) {
        const float* w = Wl + o * HC + wbase;
        acc[o] = pv.x * w[0] + pv.y * w[16] + pv.z * w[32] + pv.w * w[48];
    }
    #pragma unroll
    for (int s = 32; s > 0; s >>= 1)
        #pragma unroll
        for (int o = 0; o < NOUT; ++o)
            acc[o] += __shfl_xor(acc[o], s);
    if (lane == 0) {
        #pragma unroll
        for (int o = 0; o < NOUT; ++o)
            out[g * NOUT + o] = acc[o] + bl[o];
    }
}

// ---------------- launch ----------------

extern "C" void kernel_launch(void* const* d_in, const int* in_sizes, int n_in,
                              void* d_out, int out_size, void* d_ws, size_t ws_size,
                              hipStream_t stream) {
    (void)in_sizes; (void)n_in; (void)out_size; (void)ws_size;
    const float* x   = (const float*)d_in[0];
    const int*   ei  = (const int*)d_in[1];
    const int*   bat = (const int*)d_in[2];
    const float* W1  = (const float*)d_in[3];
    const float* as1 = (const float*)d_in[4];
    const float* ad1 = (const float*)d_in[5];
    const float* b1  = (const float*)d_in[6];
    const float* W2  = (const float*)d_in[7];
    const float* as2 = (const float*)d_in[8];
    const float* ad2 = (const float*)d_in[9];
    const float* b2  = (const float*)d_in[10];
    const float* W3  = (const float*)d_in[11];
    const float* as3 = (const float*)d_in[12];
    const float* ad3 = (const float*)d_in[13];
    const float* b3  = (const float*)d_in[14];
    const float* Wl  = (const float*)d_in[15];
    const float* bl  = (const float*)d_in[16];
    float* out = (float*)d_out;

    char* ws = (char*)d_ws;
    size_t p = 0;
    auto alloc = [&](size_t bytes) {
        size_t a = p;
        p += (bytes + 255) & ~(size_t)255;
        return a;
    };
    int*      off  = (int*)(ws + alloc((size_t)(NB196 * 256 + 256) * 4));
    int*      bcur = (int*)(ws + alloc(256 * 4));
    int*      ssrc = (int*)(ws + alloc((size_t)ETOT * 4));
    unsigned* tmp  = (unsigned*)(ws + alloc((size_t)NB196 * BCAP * 4));
    int*      bsum = (int*)(ws + alloc(256 * 4));
    float*    es   = (float*)(ws + alloc((size_t)NNODES * NHEAD * 4));
    float*    ed   = (float*)(ws + alloc((size_t)NNODES * NHEAD * 4));
    u16*      xb   = (u16*)(ws + alloc((size_t)NNODES * FIN * 2));
    u16*      w1b  = (u16*)(ws + alloc((size_t)HC * FIN * 2));
    u16*      w2b  = (u16*)(ws + alloc((size_t)HC * HC * 2));
    u16*      w3b  = (u16*)(ws + alloc((size_t)HC * HC * 2));
    u8*       Hb   = (u8*)(ws + alloc((size_t)NNODES * HC));       // fp8 e4m3, σ-layout
    u16*      Ab   = (u16*)(ws + alloc((size_t)NNODES * HC * 2));  // bf16, σ-layout
    float*    pp   = (float*)(ws + alloc((size_t)NGRAPH * 8 * HC * 4));   // pool partials
    int*      goff = (int*)(ws + alloc((size_t)(NGRAPH + 1) * 4));
    alloc(128 * 1024);   // slack: gemm A-tile over-read past row NNODES stays in d_ws

    // zero only the 196 bucket counters
    hipMemsetAsync(bcur, 0, 256 * 4, stream);

    // bf16/σ conversions
    prep_kernel<<<NBCONV, 256, 0, stream>>>(x, W1, W2, W3, xb, w1b, w2b, w3b);

    // counting sort of edges by dst (fixed-capacity buckets; off derived in pass 2)
    scatter1_kernel<<<NBS1, 256, 0, stream>>>(ei, bcur, tmp);
    scanb_kernel<<<1, 256, 0, stream>>>(bcur, bsum, bat, goff);
    scatter2_kernel<<<NB196, 256, 0, stream>>>(tmp, bcur, bsum, off, ssrc);

    dim3 ggrid((NNODES + TBM - 1) / TBM, HC / TBN);
    int nblocks4 = (NNODES + 3) / 4;   // 4 dst per block (1 per wave)

    // layer 1
    gemm_mfma<<<ggrid, 256, 0, stream>>>(xb, w1b, Hb, FIN, as1, ad1, es, ed);
    aggregate_kernel<<<nblocks4, 256, 0, stream>>>(Hb, ssrc, off, bsum, es, ed, b1, Ab, 1);
    // layer 2
    gemm_mfma<<<ggrid, 256, 0, stream>>>(Ab, w2b, Hb, HC, as2, ad2, es, ed);
    aggregate_kernel<<<nblocks4, 256, 0, stream>>>(Hb, ssrc, off, bsum, es, ed, b2, Ab, 1);
    // layer 3
    gemm_mfma<<<ggrid, 256, 0, stream>>>(Ab, w3b, Hb, HC, as3, ad3, es, ed);
    aggregate_kernel<<<nblocks4, 256, 0, stream>>>(Hb, ssrc, off, bsum, es, ed, b3, Ab, 0);

    // pool + classify
    dim3 pgrid(NGRAPH, 8);
    pool_kernel<<<pgrid, 256, 0, stream>>>(Ab, goff, pp);
    final_kernel<<<NGRAPH, 64, 0, stream>>>(pp, goff, Wl, bl, out);
}

// Round 7
// 342.853 us; speedup vs baseline: 1.1037x; 1.1037x over previous
//
#include <hip/hip_runtime.h>
#include <hip/hip_bf16.h>
#include <math.h>

#define NNODES 50000
#define NEDGES 800000
#define NGRAPH 64
#define FIN 128
#define HC 256     // H * HID
#define NHEAD 4
#define NOUT 10
#define ETOT (NEDGES + NNODES)   // edges + self-loops
#define NB196 ((NNODES + 255) / 256)   // 196 sort buckets
#define BCAP 5376                       // per-bucket capacity (15 sigma above mean 4337)
#define S1CHUNK 4096                    // edges per scatter1 block (16/thread)
#define NBS1 ((ETOT + S1CHUNK - 1) / S1CHUNK)   // 208

// Channel permutation σ (within each 64-channel head block):
//   stored p = (c & ~63) | ((c&15)<<2) | ((c>>4)&3)   [actual c -> stored p]
// Hb (fp8) and Ab (bf16) live in σ-layout; w2b/w3b K-dims σ-permuted at
// conversion; bias/Wl loads re-indexed; es/ed epilogue uses fp32 acc directly.

typedef unsigned short u16;
typedef unsigned char u8;
typedef __attribute__((ext_vector_type(8))) short short8;
typedef __attribute__((ext_vector_type(4))) float f32x4;
typedef __attribute__((ext_vector_type(2))) float f32x2;

__device__ inline u16 f2b(float f) {
    union { float f; unsigned u; } v; v.f = f;
    unsigned r = v.u + 0x7FFF + ((v.u >> 16) & 1);   // RNE (finite values)
    return (u16)(r >> 16);
}
__device__ inline float b2f(u16 u) {
    union { unsigned u; float f; } v; v.u = ((unsigned)u) << 16; return v.f;
}

__device__ inline void gload_lds16(const void* g, void* l) {
    __builtin_amdgcn_global_load_lds(
        (const __attribute__((address_space(1))) unsigned*)g,
        (__attribute__((address_space(3))) unsigned*)l, 16, 0, 0);
}

// lower_bound over sorted batch[] (0..NGRAPH values)
__device__ inline int lbound(const int* __restrict__ batch, int g) {
    int lo = 0, hi = NNODES;
    while (lo < hi) {
        int mid = (lo + hi) >> 1;
        if (batch[mid] < g) lo = mid + 1; else hi = mid;
    }
    return lo;
}

// ---------------- prep: bf16 conversions (blocks < NBCONV) fused with ----
// edge-sort pass 1 (blocks >= NBCONV). The two halves touch disjoint data;
// fusing saves a launch and overlaps BW-bound conversion with latency-bound
// edge reads. Packed u32: src (16b) | local-dst (8b) << 16.

#define CS0 (NNODES * FIN)   // 6,400,000
#define CS1 (HC * FIN)       // 32,768
#define CS2 (HC * HC)        // 65,536
#define NBCONV (((CS0 + CS1 + 2 * CS2) / 4 + 255) / 256)   // 6410

__global__ __launch_bounds__(256) void prep_kernel(const float* __restrict__ x,
                                                   const float* __restrict__ W1,
                                                   const float* __restrict__ W2,
                                                   const float* __restrict__ W3,
                                                   u16* __restrict__ xb, u16* __restrict__ w1b,
                                                   u16* __restrict__ w2b, u16* __restrict__ w3b,
                                                   const int* __restrict__ ei,
                                                   int* __restrict__ bcur,
                                                   unsigned* __restrict__ tmp) {
    __shared__ int hist[NB196];
    __shared__ int basec[NB196];
    int b = blockIdx.x;
    if (b < NBCONV) {
        long i = (long)(b * 256 + threadIdx.x) * 4;
        if (i < CS0) {
            float4 v = *(const float4*)(x + i);
            ushort4 o;
            o.x = f2b(v.x); o.y = f2b(v.y); o.z = f2b(v.z); o.w = f2b(v.w);
            *(ushort4*)(xb + i) = o;
        } else if (i < CS0 + CS1) {
            long off = i - CS0;
            float4 v = *(const float4*)(W1 + off);
            ushort4 o;
            o.x = f2b(v.x); o.y = f2b(v.y); o.z = f2b(v.z); o.w = f2b(v.w);
            *(ushort4*)(w1b + off) = o;
        } else if (i < CS0 + CS1 + 2 * CS2) {
            const float* src; u16* dst; long off;
            if (i < CS0 + CS1 + CS2) { src = W2; dst = w2b; off = i - CS0 - CS1; }
            else                     { src = W3; dst = w3b; off = i - CS0 - CS1 - CS2; }
            float4 v = *(const float4*)(src + off);
            int row = (int)(off >> 8), col = (int)(off & 255);
            float vv[4] = {v.x, v.y, v.z, v.w};
            #pragma unroll
            for (int k = 0; k < 4; ++k) {
                int c = col + k;
                int pp = (c & ~63) | ((c & 15) << 2) | ((c >> 4) & 3);
                dst[row * 256 + pp] = f2b(vv[k]);
            }
        }
        return;
    }
    // ---- edge-sort pass 1: block-aggregated atomics into fixed-cap buckets ----
    int tid = threadIdx.x;
    int e0 = (b - NBCONV) * S1CHUNK;
    for (int i = tid; i < NB196; i += 256) hist[i] = 0;
    __syncthreads();
    int bkt[16], rnk[16];
    unsigned pk[16];
    #pragma unroll
    for (int k = 0; k < 16; ++k) {
        int e = e0 + k * 256 + tid;
        bkt[k] = -1;
        if (e < ETOT) {
            int src, dstn;
            if (e < NEDGES) { src = ei[e]; dstn = ei[NEDGES + e]; }
            else            { src = dstn = e - NEDGES; }
            int bb = dstn >> 8;
            bkt[k] = bb;
            rnk[k] = atomicAdd(&hist[bb], 1);
            pk[k] = (unsigned)src | ((unsigned)(dstn & 255) << 16);
        }
    }
    __syncthreads();
    for (int i = tid; i < NB196; i += 256) {
        int h = hist[i];
        basec[i] = h ? atomicAdd(&bcur[i], h) : 0;
    }
    __syncthreads();
    #pragma unroll
    for (int k = 0; k < 16; ++k) {
        if (bkt[k] >= 0) {
            int pos = basec[bkt[k]] + rnk[k];
            if (pos < BCAP)
                tmp[(size_t)bkt[k] * BCAP + pos] = pk[k];
        }
    }
}

// ---------------- pass 2: one block per bucket. Self-computes the global ----
// bucket prefix (196-entry scan, removes the scanb kernel), stages the bucket
// in LDS, counts per-dst, block-scans 256 counters -> writes GLOBAL CSR
// offsets off[] (aggregate then needs no bsum), ranks+scatters, copies out.

__global__ __launch_bounds__(256) void scatter2_kernel(const unsigned* __restrict__ tmp,
                                                       const int* __restrict__ bcur,
                                                       int* __restrict__ off,
                                                       int* __restrict__ ssrc) {
    __shared__ unsigned ebuf[BCAP];
    __shared__ int ldss[BCAP];
    __shared__ int cnt[256];
    __shared__ int loff[256];
    __shared__ int ws[4];
    __shared__ int sbase;
    int b = blockIdx.x;
    int tid = threadIdx.x;
    int lane = tid & 63, wid = tid >> 6;

    // global prefix of clamped bucket totals (exclusive, at index b)
    int bv = 0;
    if (tid < NB196) { bv = bcur[tid]; if (bv > BCAP) bv = BCAP; }
    {
        int x = bv;
        #pragma unroll
        for (int o = 1; o < 64; o <<= 1) {
            int t = __shfl_up(x, o);
            if (lane >= o) x += t;
        }
        if (lane == 63) ws[wid] = x;
        __syncthreads();
        if (tid < 4) {
            int w = ws[tid];
            #pragma unroll
            for (int o = 1; o < 4; o <<= 1) {
                int t = __shfl_up(w, o, 4);
                if ((tid & 3) >= o) w += t;
            }
            ws[tid] = w;
        }
        __syncthreads();
        int wexcl = wid ? ws[wid - 1] : 0;
        int gexcl = x - bv + wexcl;
        if (tid == b) sbase = gexcl;
        __syncthreads();
    }
    int s = sbase;
    int n = bcur[b];
    if (n > BCAP) n = BCAP;

    cnt[tid] = 0;
    const unsigned* tb = tmp + (size_t)b * BCAP;
    for (int i = tid; i < n; i += 256) ebuf[i] = tb[i];
    __syncthreads();
    for (int i = tid; i < n; i += 256) atomicAdd(&cnt[ebuf[i] >> 16], 1);
    __syncthreads();
    // block exclusive scan of cnt[256]
    int v = cnt[tid];
    int x = v;
    #pragma unroll
    for (int o = 1; o < 64; o <<= 1) {
        int t = __shfl_up(x, o);
        if (lane >= o) x += t;
    }
    if (lane == 63) ws[wid] = x;
    __syncthreads();
    if (tid < 4) {
        int w = ws[tid];
        #pragma unroll
        for (int o = 1; o < 4; o <<= 1) {
            int t = __shfl_up(w, o, 4);
            if ((tid & 3) >= o) w += t;
        }
        ws[tid] = w;
    }
    __syncthreads();
    int wexcl = wid ? ws[wid - 1] : 0;
    int excl = x - v + wexcl;
    loff[tid] = excl;
    off[b * 256 + tid] = s + excl;   // GLOBAL CSR offset
    cnt[tid] = 0;
    __syncthreads();
    for (int i = tid; i < n; i += 256) {
        unsigned pk = ebuf[i];
        int ld = (int)(pk >> 16);
        int rank = atomicAdd(&cnt[ld], 1);
        ldss[loff[ld] + rank] = (int)(pk & 0xFFFFu);
    }
    __syncthreads();
    for (int i = tid; i < n; i += 256) ssrc[s + i] = ldss[i];
}

// ---------------- bf16 MFMA GEMM + fused e_src/e_dst epilogue ----------------

#define TBM 128
#define TBN 128
#define TBK 32

__global__ __launch_bounds__(256) void gemm_mfma(const u16* __restrict__ A,
                                                 const u16* __restrict__ B,
                                                 u8* __restrict__ C, int K,
                                                 const float* __restrict__ asrc,
                                                 const float* __restrict__ adst,
                                                 float* __restrict__ es,
                                                 float* __restrict__ ed) {
    __shared__ u16 Als[TBM * TBK];   // 8 KB
    __shared__ u16 Bls[TBN * TBK];   // 8 KB
    int tid = threadIdx.x;
    int wave = tid >> 6, lane = tid & 63;
    int brow = blockIdx.x * TBM, bcol = blockIdx.y * TBN;
    int m_base = (wave >> 1) * 64, n_base = (wave & 1) * 64;
    int r0 = tid >> 2, kc = (tid & 3) * 8;
    int lquad = lane >> 4, l16 = lane & 15;

    f32x4 acc[4][4] = {};

    const u16* ga0 = A + (size_t)(brow + r0) * K + kc;
    const u16* ga1 = A + (size_t)(brow + 64 + r0) * K + kc;
    const u16* gb0 = B + (size_t)(bcol + r0) * K + kc;
    const u16* gb1 = B + (size_t)(bcol + 64 + r0) * K + kc;
    u16* la0 = &Als[r0 * TBK + kc];          // byte offset == tid*16 (wave-contiguous)
    u16* la1 = &Als[(64 + r0) * TBK + kc];
    u16* lb0 = &Bls[r0 * TBK + kc];
    u16* lb1 = &Bls[(64 + r0) * TBK + kc];

    for (int k0 = 0; k0 < K; k0 += TBK) {
        __syncthreads();
        gload_lds16(ga0 + k0, la0);
        gload_lds16(ga1 + k0, la1);
        gload_lds16(gb0 + k0, lb0);
        gload_lds16(gb1 + k0, lb1);
        __syncthreads();
        short8 fa[4], fb[4];
        #pragma unroll
        for (int i = 0; i < 4; ++i) {
            fa[i] = *(const short8*)(&Als[(m_base + i * 16 + l16) * TBK + lquad * 8]);
            fb[i] = *(const short8*)(&Bls[(n_base + i * 16 + l16) * TBK + lquad * 8]);
        }
        #pragma unroll
        for (int i = 0; i < 4; ++i)
            #pragma unroll
            for (int j = 0; j < 4; ++j)
                acc[i][j] = __builtin_amdgcn_mfma_f32_16x16x32_bf16(fa[i], fb[j], acc[i][j], 0, 0, 0);
    }

    // fp8 σ-layout C store: stored bytes n_base+l16*4+{0..3} = acc[i][0..3][r]
    #pragma unroll
    for (int i = 0; i < 4; ++i) {
        int rbase = brow + m_base + i * 16 + lquad * 4;
        #pragma unroll
        for (int r = 0; r < 4; ++r) {
            int row = rbase + r;
            if (row < NNODES) {
                int u = 0;
                u = __builtin_amdgcn_cvt_pk_fp8_f32(acc[i][0][r], acc[i][1][r], u, false);
                u = __builtin_amdgcn_cvt_pk_fp8_f32(acc[i][2][r], acc[i][3][r], u, true);
                *(int*)(C + (size_t)row * HC + bcol + n_base + l16 * 4) = u;
            }
        }
    }

    // fused attention-scalar epilogue (fp32 accumulators — full precision)
    int head = (bcol + n_base) >> 6;
    float asv[4], adv[4];
    #pragma unroll
    for (int j = 0; j < 4; ++j) {
        asv[j] = asrc[head * 64 + j * 16 + l16];
        adv[j] = adst[head * 64 + j * 16 + l16];
    }
    #pragma unroll
    for (int i = 0; i < 4; ++i) {
        #pragma unroll
        for (int r = 0; r < 4; ++r) {
            float ps = 0.f, pd = 0.f;
            #pragma unroll
            for (int j = 0; j < 4; ++j) {
                ps = fmaf(acc[i][j][r], asv[j], ps);
                pd = fmaf(acc[i][j][r], adv[j], pd);
            }
            #pragma unroll
            for (int o = 1; o < 16; o <<= 1) {
                ps += __shfl_xor(ps, o);
                pd += __shfl_xor(pd, o);
            }
            int row = brow + m_base + i * 16 + lquad * 4 + r;
            if (l16 == 0 && row < NNODES) {
                es[row * 4 + head] = ps;
                ed[row * 4 + head] = pd;
            }
        }
    }
}

// ---------------- aggregate: session-start structure (best measured at scale: ----
// 4 dst/block 1/wave, 16-edge chunks staged via LDS slots, 64-lane 4B
// coalesced row gathers, 16-deep unrolled main loop + runtime remainder).
// Only change vs original: global CSR off[] (no bsum loads).

__global__ __launch_bounds__(256) void aggregate_kernel(const u8* __restrict__ h,
                                                        const int* __restrict__ ssrc,
                                                        const int* __restrict__ off,
                                                        const float* __restrict__ es,
                                                        const float* __restrict__ ed,
                                                        const float* __restrict__ bias,
                                                        u16* __restrict__ out,
                                                        int apply_elu) {
    __shared__ int2 xch[4][4][17];   // [wave][head][16 edges + pad]
    const unsigned* h32 = (const unsigned*)h;   // 64 uints per row (σ-layout)
    int wid = threadIdx.x >> 6;
    int dst = blockIdx.x * 4 + wid;
    if (dst >= NNODES) return;
    int lane = threadIdx.x & 63;
    int head = lane >> 4;
    int j16 = lane & 15;
    int s = off[dst];
    int e = off[dst + 1];
    float edh = ed[dst * 4 + head];
    int2* myslot = &xch[wid][head][0];

    float a0 = 0.f, a1 = 0.f, a2 = 0.f, a3 = 0.f, dpriv = 0.f;

    int base = s;
    for (; base + 16 <= e; base += 16) {
        int mysrc = ssrc[base + j16];
        float l = es[mysrc * 4 + head] + edh;
        l = fmaxf(l, 0.2f * l);
        float myex = __expf(l);
        dpriv += myex;
        myslot[j16] = make_int2(mysrc, __float_as_int(myex));
        #pragma unroll
        for (int j = 0; j < 16; ++j) {
            int2 pr = myslot[j];
            float exj = __int_as_float(pr.y);
            unsigned hv = h32[(unsigned)pr.x * 64 + lane];
            f32x2 lo = __builtin_amdgcn_cvt_pk_f32_fp8(hv, false);
            f32x2 hi = __builtin_amdgcn_cvt_pk_f32_fp8(hv, true);
            a0 += lo.x * exj;
            a1 += lo.y * exj;
            a2 += hi.x * exj;
            a3 += hi.y * exj;
        }
    }
    int cnt = e - base;
    if (cnt > 0) {
        int mysrc = 0; float myex = 0.f;
        if (j16 < cnt) {
            mysrc = ssrc[base + j16];
            float l = es[mysrc * 4 + head] + edh;
            l = fmaxf(l, 0.2f * l);
            myex = __expf(l);
            dpriv += myex;
        }
        myslot[j16] = make_int2(mysrc, __float_as_int(myex));
        for (int j = 0; j < cnt; ++j) {
            int2 pr = myslot[j];
            float exj = __int_as_float(pr.y);
            unsigned hv = h32[(unsigned)pr.x * 64 + lane];
            f32x2 lo = __builtin_amdgcn_cvt_pk_f32_fp8(hv, false);
            f32x2 hi = __builtin_amdgcn_cvt_pk_f32_fp8(hv, true);
            a0 += lo.x * exj;
            a1 += lo.y * exj;
            a2 += hi.x * exj;
            a3 += hi.y * exj;
        }
    }
    // denom: sum dpriv across the 16 lanes of this head group
    #pragma unroll
    for (int o = 1; o < 16; o <<= 1) dpriv += __shfl_xor(dpriv, o);
    float inv = 1.f / (dpriv + 1e-16f);
    // bias for stored positions lane*4+{0..3} = actual 64*(lane>>4)+(lane&15)+{0,16,32,48}
    int bbase = ((lane >> 4) << 6) | (lane & 15);
    float b0 = bias[bbase], b1 = bias[bbase + 16], b2 = bias[bbase + 32], b3 = bias[bbase + 48];
    float o0 = a0 * inv + b0;
    float o1 = a1 * inv + b1;
    float o2 = a2 * inv + b2;
    float o3 = a3 * inv + b3;
    if (apply_elu) {
        o0 = o0 > 0.f ? o0 : __expf(o0) - 1.f;
        o1 = o1 > 0.f ? o1 : __expf(o1) - 1.f;
        o2 = o2 > 0.f ? o2 : __expf(o2) - 1.f;
        o3 = o3 > 0.f ? o3 : __expf(o3) - 1.f;
    }
    ushort4 ov;
    ov.x = f2b(o0); ov.y = f2b(o1); ov.z = f2b(o2); ov.w = f2b(o3);
    *(ushort4*)(out + (size_t)dst * HC + lane * 4) = ov;
}

// ---------------- sliced mean-pool partials: block = (graph, 8 node-slices). ----
// Graph bounds via binary search on batch (scanb kernel eliminated).

__global__ __launch_bounds__(256) void pool_kernel(const u16* __restrict__ hin,
                                                   const int* __restrict__ batch,
                                                   float* __restrict__ pp) {
    int g = blockIdx.x;
    int slice = blockIdx.y;            // 0..7
    int lane = threadIdx.x & 63;
    int wid = threadIdx.x >> 6;
    int s = lbound(batch, g), e = lbound(batch, g + 1);
    float a0 = 0.f, a1 = 0.f, a2 = 0.f, a3 = 0.f;
    for (int n = s + slice * 4 + wid; n < e; n += 32) {
        ushort4 hv = *(const ushort4*)(hin + (size_t)n * HC + lane * 4);
        a0 += b2f(hv.x); a1 += b2f(hv.y); a2 += b2f(hv.z); a3 += b2f(hv.w);
    }
    __shared__ float4 part[4][64];
    part[wid][lane] = make_float4(a0, a1, a2, a3);
    __syncthreads();
    if (wid == 0) {
        float4 p0 = part[0][lane], p1 = part[1][lane], p2 = part[2][lane], p3 = part[3][lane];
        float4 v = make_float4((p0.x + p1.x) + (p2.x + p3.x),
                               (p0.y + p1.y) + (p2.y + p3.y),
                               (p0.z + p1.z) + (p2.z + p3.z),
                               (p0.w + p1.w) + (p2.w + p3.w));
        *(float4*)(pp + ((size_t)(g * 8 + slice)) * HC + lane * 4) = v;
    }
}

// ---------------- final classifier: sum 8 slice-partials, mean, Wl dot ----------------

__global__ __launch_bounds__(64) void final_kernel(const float* __restrict__ pp,
                                                   const int* __restrict__ batch,
                                                   const float* __restrict__ Wl,
                                                   const float* __restrict__ bl,
                                                   float* __restrict__ out) {
    int g = blockIdx.x;
    int lane = threadIdx.x;
    float4 pv = make_float4(0.f, 0.f, 0.f, 0.f);
    #pragma unroll
    for (int sl = 0; sl < 8; ++sl) {
        float4 v = *(const float4*)(pp + ((size_t)(g * 8 + sl)) * HC + lane * 4);
        pv.x += v.x; pv.y += v.y; pv.z += v.z; pv.w += v.w;
    }
    int cs = lbound(batch, g), ce = lbound(batch, g + 1);
    float cntf = fmaxf((float)(ce - cs), 1.f);
    float inv = 1.f / cntf;
    pv.x *= inv; pv.y *= inv; pv.z *= inv; pv.w *= inv;
    int wbase = ((lane >> 4) << 6) | (lane & 15);             // actual ch = wbase+{0,16,32,48}
    float acc[NOUT];
    #pragma unroll
    for (int o = 0; o < NOUT; ++o) {
        const float* w = Wl + o * HC + wbase;
        acc[o] = pv.x * w[0] + pv.y * w[16] + pv.z * w[32] + pv.w * w[48];
    }
    #pragma unroll
    for (int s = 32; s > 0; s >>= 1)
        #pragma unroll
        for (int o = 0; o < NOUT; ++o)
            acc[o] += __shfl_xor(acc[o], s);
    if (lane == 0) {
        #pragma unroll
        for (int o = 0; o < NOUT; ++o)
            out[g * NOUT + o] = acc[o] + bl[o];
    }
}

// ---------------- launch ----------------

extern "C" void kernel_launch(void* const* d_in, const int* in_sizes, int n_in,
                              void* d_out, int out_size, void* d_ws, size_t ws_size,
                              hipStream_t stream) {
    (void)in_sizes; (void)n_in; (void)out_size; (void)ws_size;
    const float* x   = (const float*)d_in[0];
    const int*   ei  = (const int*)d_in[1];
    const int*   bat = (const int*)d_in[2];
    const float* W1  = (const float*)d_in[3];
    const float* as1 = (const float*)d_in[4];
    const float* ad1 = (const float*)d_in[5];
    const float* b1  = (const float*)d_in[6];
    const float* W2  = (const float*)d_in[7];
    const float* as2 = (const float*)d_in[8];
    const float* ad2 = (const float*)d_in[9];
    const float* b2  = (const float*)d_in[10];
    const float* W3  = (const float*)d_in[11];
    const float* as3 = (const float*)d_in[12];
    const float* ad3 = (const float*)d_in[13];
    const float* b3  = (const float*)d_in[14];
    const float* Wl  = (const float*)d_in[15];
    const float* bl  = (const float*)d_in[16];
    float* out = (float*)d_out;

    char* ws = (char*)d_ws;
    size_t p = 0;
    auto alloc = [&](size_t bytes) {
        size_t a = p;
        p += (bytes + 255) & ~(size_t)255;
        return a;
    };
    int*      off  = (int*)(ws + alloc((size_t)(NB196 * 256 + 256) * 4));
    int*      bcur = (int*)(ws + alloc(256 * 4));
    int*      ssrc = (int*)(ws + alloc((size_t)ETOT * 4));
    unsigned* tmp  = (unsigned*)(ws + alloc((size_t)NB196 * BCAP * 4));
    float*    es   = (float*)(ws + alloc((size_t)NNODES * NHEAD * 4));
    float*    ed   = (float*)(ws + alloc((size_t)NNODES * NHEAD * 4));
    u16*      xb   = (u16*)(ws + alloc((size_t)NNODES * FIN * 2));
    u16*      w1b  = (u16*)(ws + alloc((size_t)HC * FIN * 2));
    u16*      w2b  = (u16*)(ws + alloc((size_t)HC * HC * 2));
    u16*      w3b  = (u16*)(ws + alloc((size_t)HC * HC * 2));
    u8*       Hb   = (u8*)(ws + alloc((size_t)NNODES * HC));       // fp8 e4m3, σ-layout
    u16*      Ab   = (u16*)(ws + alloc((size_t)NNODES * HC * 2));  // bf16, σ-layout
    float*    pp   = (float*)(ws + alloc((size_t)NGRAPH * 8 * HC * 4));   // pool partials
    alloc(128 * 1024);   // slack: gemm A-tile over-read past row NNODES stays in d_ws

    // zero only the 196 bucket counters
    hipMemsetAsync(bcur, 0, 256 * 4, stream);

    // conversions + edge-sort pass 1 (fused, disjoint block ranges)
    prep_kernel<<<NBCONV + NBS1, 256, 0, stream>>>(x, W1, W2, W3, xb, w1b, w2b, w3b,
                                                   ei, bcur, tmp);
    // edge-sort pass 2 (self-computes global prefix; writes global CSR off[])
    scatter2_kernel<<<NB196, 256, 0, stream>>>(tmp, bcur, off, ssrc);

    dim3 ggrid((NNODES + TBM - 1) / TBM, HC / TBN);
    int nblocks4 = (NNODES + 3) / 4;   // 4 dst per block (1 per wave)

    // layer 1
    gemm_mfma<<<ggrid, 256, 0, stream>>>(xb, w1b, Hb, FIN, as1, ad1, es, ed);
    aggregate_kernel<<<nblocks4, 256, 0, stream>>>(Hb, ssrc, off, es, ed, b1, Ab, 1);
    // layer 2
    gemm_mfma<<<ggrid, 256, 0, stream>>>(Ab, w2b, Hb, HC, as2, ad2, es, ed);
    aggregate_kernel<<<nblocks4, 256, 0, stream>>>(Hb, ssrc, off, es, ed, b2, Ab, 1);
    // layer 3
    gemm_mfma<<<ggrid, 256, 0, stream>>>(Ab, w3b, Hb, HC, as3, ad3, es, ed);
    aggregate_kernel<<<nblocks4, 256, 0, stream>>>(Hb, ssrc, off, es, ed, b3, Ab, 0);

    // pool + classify
    dim3 pgrid(NGRAPH, 8);
    pool_kernel<<<pgrid, 256, 0, stream>>>(Ab, bat, pp);
    final_kernel<<<NGRAPH, 64, 0, stream>>>(pp, bat, Wl, bl, out);
}

// Round 8
// 338.149 us; speedup vs baseline: 1.1191x; 1.0139x over previous
//
#include <hip/hip_runtime.h>
#include <hip/hip_bf16.h>
#include <math.h>

#define NNODES 50000
#define NEDGES 800000
#define NGRAPH 64
#define FIN 128
#define HC 256     // H * HID
#define NHEAD 4
#define NOUT 10
#define ETOT (NEDGES + NNODES)   // edges + self-loops
#define NB196 ((NNODES + 255) / 256)   // 196 sort buckets
#define BCAP 5376                       // per-bucket capacity (15 sigma above mean 4337)
#define S1CHUNK 4096                    // edges per scatter1 block (16/thread)
#define NBS1 ((ETOT + S1CHUNK - 1) / S1CHUNK)   // 208

// Channel permutation σ (within each 64-channel head block):
//   stored p = (c & ~63) | ((c&15)<<2) | ((c>>4)&3)   [actual c -> stored p]
// Hb (fp8) and Ab (bf16) live in σ-layout; w2b/w3b K-dims σ-permuted at
// conversion; bias/Wl loads re-indexed; es/ed epilogue uses fp32 acc directly.

typedef unsigned short u16;
typedef unsigned char u8;
typedef __attribute__((ext_vector_type(8))) short short8;
typedef __attribute__((ext_vector_type(4))) float f32x4;
typedef __attribute__((ext_vector_type(2))) float f32x2;

__device__ inline u16 f2b(float f) {
    union { float f; unsigned u; } v; v.f = f;
    unsigned r = v.u + 0x7FFF + ((v.u >> 16) & 1);   // RNE (finite values)
    return (u16)(r >> 16);
}
__device__ inline float b2f(u16 u) {
    union { unsigned u; float f; } v; v.u = ((unsigned)u) << 16; return v.f;
}

__device__ inline void gload_lds16(const void* g, void* l) {
    __builtin_amdgcn_global_load_lds(
        (const __attribute__((address_space(1))) unsigned*)g,
        (__attribute__((address_space(3))) unsigned*)l, 16, 0, 0);
}

// lower_bound over sorted batch[] (0..NGRAPH values)
__device__ inline int lbound(const int* __restrict__ batch, int g) {
    int lo = 0, hi = NNODES;
    while (lo < hi) {
        int mid = (lo + hi) >> 1;
        if (batch[mid] < g) lo = mid + 1; else hi = mid;
    }
    return lo;
}

// ---------------- prep: bf16 conversions (blocks < NBCONV) fused with ----
// edge-sort pass 1 (blocks >= NBCONV). Packed u32: src | local-dst << 16.

#define CS0 (NNODES * FIN)   // 6,400,000
#define CS1 (HC * FIN)       // 32,768
#define CS2 (HC * HC)        // 65,536
#define NBCONV (((CS0 + CS1 + 2 * CS2) / 4 + 255) / 256)   // 6410

__global__ __launch_bounds__(256) void prep_kernel(const float* __restrict__ x,
                                                   const float* __restrict__ W1,
                                                   const float* __restrict__ W2,
                                                   const float* __restrict__ W3,
                                                   u16* __restrict__ xb, u16* __restrict__ w1b,
                                                   u16* __restrict__ w2b, u16* __restrict__ w3b,
                                                   const int* __restrict__ ei,
                                                   int* __restrict__ bcur,
                                                   unsigned* __restrict__ tmp) {
    __shared__ int hist[NB196];
    __shared__ int basec[NB196];
    int b = blockIdx.x;
    if (b < NBCONV) {
        long i = (long)(b * 256 + threadIdx.x) * 4;
        if (i < CS0) {
            float4 v = *(const float4*)(x + i);
            ushort4 o;
            o.x = f2b(v.x); o.y = f2b(v.y); o.z = f2b(v.z); o.w = f2b(v.w);
            *(ushort4*)(xb + i) = o;
        } else if (i < CS0 + CS1) {
            long off = i - CS0;
            float4 v = *(const float4*)(W1 + off);
            ushort4 o;
            o.x = f2b(v.x); o.y = f2b(v.y); o.z = f2b(v.z); o.w = f2b(v.w);
            *(ushort4*)(w1b + off) = o;
        } else if (i < CS0 + CS1 + 2 * CS2) {
            const float* src; u16* dst; long off;
            if (i < CS0 + CS1 + CS2) { src = W2; dst = w2b; off = i - CS0 - CS1; }
            else                     { src = W3; dst = w3b; off = i - CS0 - CS1 - CS2; }
            float4 v = *(const float4*)(src + off);
            int row = (int)(off >> 8), col = (int)(off & 255);
            float vv[4] = {v.x, v.y, v.z, v.w};
            #pragma unroll
            for (int k = 0; k < 4; ++k) {
                int c = col + k;
                int pp = (c & ~63) | ((c & 15) << 2) | ((c >> 4) & 3);
                dst[row * 256 + pp] = f2b(vv[k]);
            }
        }
        return;
    }
    // ---- edge-sort pass 1: block-aggregated atomics into fixed-cap buckets ----
    int tid = threadIdx.x;
    int e0 = (b - NBCONV) * S1CHUNK;
    for (int i = tid; i < NB196; i += 256) hist[i] = 0;
    __syncthreads();
    int bkt[16], rnk[16];
    unsigned pk[16];
    #pragma unroll
    for (int k = 0; k < 16; ++k) {
        int e = e0 + k * 256 + tid;
        bkt[k] = -1;
        if (e < ETOT) {
            int src, dstn;
            if (e < NEDGES) { src = ei[e]; dstn = ei[NEDGES + e]; }
            else            { src = dstn = e - NEDGES; }
            int bb = dstn >> 8;
            bkt[k] = bb;
            rnk[k] = atomicAdd(&hist[bb], 1);
            pk[k] = (unsigned)src | ((unsigned)(dstn & 255) << 16);
        }
    }
    __syncthreads();
    for (int i = tid; i < NB196; i += 256) {
        int h = hist[i];
        basec[i] = h ? atomicAdd(&bcur[i], h) : 0;
    }
    __syncthreads();
    #pragma unroll
    for (int k = 0; k < 16; ++k) {
        if (bkt[k] >= 0) {
            int pos = basec[bkt[k]] + rnk[k];
            if (pos < BCAP)
                tmp[(size_t)bkt[k] * BCAP + pos] = pk[k];
        }
    }
}

// ---------------- pass 2: one block per bucket. Self-computes the global ----
// bucket prefix, stages the bucket in LDS, counts per-dst, block-scans 256
// counters -> writes GLOBAL CSR offsets off[], ranks+scatters, copies out.

__global__ __launch_bounds__(256) void scatter2_kernel(const unsigned* __restrict__ tmp,
                                                       const int* __restrict__ bcur,
                                                       int* __restrict__ off,
                                                       int* __restrict__ ssrc) {
    __shared__ unsigned ebuf[BCAP];
    __shared__ int ldss[BCAP];
    __shared__ int cnt[256];
    __shared__ int loff[256];
    __shared__ int ws[4];
    __shared__ int sbase;
    int b = blockIdx.x;
    int tid = threadIdx.x;
    int lane = tid & 63, wid = tid >> 6;

    // global prefix of clamped bucket totals (exclusive, at index b)
    int bv = 0;
    if (tid < NB196) { bv = bcur[tid]; if (bv > BCAP) bv = BCAP; }
    {
        int x = bv;
        #pragma unroll
        for (int o = 1; o < 64; o <<= 1) {
            int t = __shfl_up(x, o);
            if (lane >= o) x += t;
        }
        if (lane == 63) ws[wid] = x;
        __syncthreads();
        if (tid < 4) {
            int w = ws[tid];
            #pragma unroll
            for (int o = 1; o < 4; o <<= 1) {
                int t = __shfl_up(w, o, 4);
                if ((tid & 3) >= o) w += t;
            }
            ws[tid] = w;
        }
        __syncthreads();
        int wexcl = wid ? ws[wid - 1] : 0;
        int gexcl = x - bv + wexcl;
        if (tid == b) sbase = gexcl;
        __syncthreads();
    }
    int s = sbase;
    int n = bcur[b];
    if (n > BCAP) n = BCAP;

    cnt[tid] = 0;
    const unsigned* tb = tmp + (size_t)b * BCAP;
    for (int i = tid; i < n; i += 256) ebuf[i] = tb[i];
    __syncthreads();
    for (int i = tid; i < n; i += 256) atomicAdd(&cnt[ebuf[i] >> 16], 1);
    __syncthreads();
    // block exclusive scan of cnt[256]
    int v = cnt[tid];
    int x = v;
    #pragma unroll
    for (int o = 1; o < 64; o <<= 1) {
        int t = __shfl_up(x, o);
        if (lane >= o) x += t;
    }
    if (lane == 63) ws[wid] = x;
    __syncthreads();
    if (tid < 4) {
        int w = ws[tid];
        #pragma unroll
        for (int o = 1; o < 4; o <<= 1) {
            int t = __shfl_up(w, o, 4);
            if ((tid & 3) >= o) w += t;
        }
        ws[tid] = w;
    }
    __syncthreads();
    int wexcl = wid ? ws[wid - 1] : 0;
    int excl = x - v + wexcl;
    loff[tid] = excl;
    off[b * 256 + tid] = s + excl;   // GLOBAL CSR offset
    cnt[tid] = 0;
    __syncthreads();
    for (int i = tid; i < n; i += 256) {
        unsigned pk = ebuf[i];
        int ld = (int)(pk >> 16);
        int rank = atomicAdd(&cnt[ld], 1);
        ldss[loff[ld] + rank] = (int)(pk & 0xFFFFu);
    }
    __syncthreads();
    for (int i = tid; i < n; i += 256) ssrc[s + i] = ldss[i];
}

// ---------------- bf16 MFMA GEMM + fused e_src/e_dst epilogue ----------------
// R8: BK=64 (halves barrier-drain rounds; 4 iters at K=256, 2 at K=128) +
// T2 XOR swizzle: linear global_load_lds dest (tid*16) with PRE-SWIZZLED
// per-lane global column (sc ^ (row&7)); fragment reads apply the same XOR.
// Read banks become slotcol-only -> 16 lanes span all 32 banks 2-way (free),
// vs 8-way conflict of the unswizzled 64B/128B row stride.

#define TBM 128
#define TBN 128
#define TBK 64

__global__ __launch_bounds__(256) void gemm_mfma(const u16* __restrict__ A,
                                                 const u16* __restrict__ B,
                                                 u8* __restrict__ C, int K,
                                                 const float* __restrict__ asrc,
                                                 const float* __restrict__ adst,
                                                 float* __restrict__ es,
                                                 float* __restrict__ ed) {
    __shared__ u16 Als[TBM * TBK];   // 16 KB
    __shared__ u16 Bls[TBN * TBK];   // 16 KB
    int tid = threadIdx.x;
    int wave = tid >> 6, lane = tid & 63;
    int brow = blockIdx.x * TBM, bcol = blockIdx.y * TBN;
    int m_base = (wave >> 1) * 64, n_base = (wave & 1) * 64;
    int lquad = lane >> 4, l16 = lane & 15;

    // staging geometry: round q covers rows 32q..32q+31; 8 16B-slots per row
    int r_loc = tid >> 3;                    // 0..31
    int sc    = tid & 7;                     // slot-col
    int kcs   = (sc ^ (r_loc & 7)) * 8;      // swizzled logical col (u16)

    f32x4 acc[4][4] = {};

    const u16* gaBase = A + (size_t)(brow + r_loc) * K + kcs;
    const u16* gbBase = B + (size_t)(bcol + r_loc) * K + kcs;
    u16* laBase = &Als[tid * 8];             // byte = tid*16 (wave-contiguous)
    u16* lbBase = &Bls[tid * 8];

    for (int k0 = 0; k0 < K; k0 += TBK) {
        __syncthreads();
        #pragma unroll
        for (int q = 0; q < 4; ++q) {
            gload_lds16(gaBase + (size_t)(q * 32) * K + k0, laBase + q * 2048);
            gload_lds16(gbBase + (size_t)(q * 32) * K + k0, lbBase + q * 2048);
        }
        __syncthreads();
        #pragma unroll
        for (int kh = 0; kh < 2; ++kh) {
            short8 fa[4], fb[4];
            int ca = kh * 4 + lquad;         // logical 16B-group (0..7)
            #pragma unroll
            for (int i = 0; i < 4; ++i) {
                int Ra = m_base + i * 16 + l16;
                int Rb = n_base + i * 16 + l16;
                fa[i] = *(const short8*)(&Als[Ra * 64 + ((ca ^ (Ra & 7)) * 8)]);
                fb[i] = *(const short8*)(&Bls[Rb * 64 + ((ca ^ (Rb & 7)) * 8)]);
            }
            #pragma unroll
            for (int i = 0; i < 4; ++i)
                #pragma unroll
                for (int j = 0; j < 4; ++j)
                    acc[i][j] = __builtin_amdgcn_mfma_f32_16x16x32_bf16(fa[i], fb[j], acc[i][j], 0, 0, 0);
        }
    }

    // fp8 σ-layout C store: stored bytes n_base+l16*4+{0..3} = acc[i][0..3][r]
    #pragma unroll
    for (int i = 0; i < 4; ++i) {
        int rbase = brow + m_base + i * 16 + lquad * 4;
        #pragma unroll
        for (int r = 0; r < 4; ++r) {
            int row = rbase + r;
            if (row < NNODES) {
                int u = 0;
                u = __builtin_amdgcn_cvt_pk_fp8_f32(acc[i][0][r], acc[i][1][r], u, false);
                u = __builtin_amdgcn_cvt_pk_fp8_f32(acc[i][2][r], acc[i][3][r], u, true);
                *(int*)(C + (size_t)row * HC + bcol + n_base + l16 * 4) = u;
            }
        }
    }

    // fused attention-scalar epilogue (fp32 accumulators — full precision)
    int head = (bcol + n_base) >> 6;
    float asv[4], adv[4];
    #pragma unroll
    for (int j = 0; j < 4; ++j) {
        asv[j] = asrc[head * 64 + j * 16 + l16];
        adv[j] = adst[head * 64 + j * 16 + l16];
    }
    #pragma unroll
    for (int i = 0; i < 4; ++i) {
        #pragma unroll
        for (int r = 0; r < 4; ++r) {
            float ps = 0.f, pd = 0.f;
            #pragma unroll
            for (int j = 0; j < 4; ++j) {
                ps = fmaf(acc[i][j][r], asv[j], ps);
                pd = fmaf(acc[i][j][r], adv[j], pd);
            }
            #pragma unroll
            for (int o = 1; o < 16; o <<= 1) {
                ps += __shfl_xor(ps, o);
                pd += __shfl_xor(pd, o);
            }
            int row = brow + m_base + i * 16 + lquad * 4 + r;
            if (l16 == 0 && row < NNODES) {
                es[row * 4 + head] = ps;
                ed[row * 4 + head] = pd;
            }
        }
    }
}

// ---------------- aggregate: session-start structure (best measured), ----
// global CSR off[] (no bsum loads).

__global__ __launch_bounds__(256) void aggregate_kernel(const u8* __restrict__ h,
                                                        const int* __restrict__ ssrc,
                                                        const int* __restrict__ off,
                                                        const float* __restrict__ es,
                                                        const float* __restrict__ ed,
                                                        const float* __restrict__ bias,
                                                        u16* __restrict__ out,
                                                        int apply_elu) {
    __shared__ int2 xch[4][4][17];   // [wave][head][16 edges + pad]
    const unsigned* h32 = (const unsigned*)h;   // 64 uints per row (σ-layout)
    int wid = threadIdx.x >> 6;
    int dst = blockIdx.x * 4 + wid;
    if (dst >= NNODES) return;
    int lane = threadIdx.x & 63;
    int head = lane >> 4;
    int j16 = lane & 15;
    int s = off[dst];
    int e = off[dst + 1];
    float edh = ed[dst * 4 + head];
    int2* myslot = &xch[wid][head][0];

    float a0 = 0.f, a1 = 0.f, a2 = 0.f, a3 = 0.f, dpriv = 0.f;

    int base = s;
    for (; base + 16 <= e; base += 16) {
        int mysrc = ssrc[base + j16];
        float l = es[mysrc * 4 + head] + edh;
        l = fmaxf(l, 0.2f * l);
        float myex = __expf(l);
        dpriv += myex;
        myslot[j16] = make_int2(mysrc, __float_as_int(myex));
        #pragma unroll
        for (int j = 0; j < 16; ++j) {
            int2 pr = myslot[j];
            float exj = __int_as_float(pr.y);
            unsigned hv = h32[(unsigned)pr.x * 64 + lane];
            f32x2 lo = __builtin_amdgcn_cvt_pk_f32_fp8(hv, false);
            f32x2 hi = __builtin_amdgcn_cvt_pk_f32_fp8(hv, true);
            a0 += lo.x * exj;
            a1 += lo.y * exj;
            a2 += hi.x * exj;
            a3 += hi.y * exj;
        }
    }
    int cnt = e - base;
    if (cnt > 0) {
        int mysrc = 0; float myex = 0.f;
        if (j16 < cnt) {
            mysrc = ssrc[base + j16];
            float l = es[mysrc * 4 + head] + edh;
            l = fmaxf(l, 0.2f * l);
            myex = __expf(l);
            dpriv += myex;
        }
        myslot[j16] = make_int2(mysrc, __float_as_int(myex));
        for (int j = 0; j < cnt; ++j) {
            int2 pr = myslot[j];
            float exj = __int_as_float(pr.y);
            unsigned hv = h32[(unsigned)pr.x * 64 + lane];
            f32x2 lo = __builtin_amdgcn_cvt_pk_f32_fp8(hv, false);
            f32x2 hi = __builtin_amdgcn_cvt_pk_f32_fp8(hv, true);
            a0 += lo.x * exj;
            a1 += lo.y * exj;
            a2 += hi.x * exj;
            a3 += hi.y * exj;
        }
    }
    // denom: sum dpriv across the 16 lanes of this head group
    #pragma unroll
    for (int o = 1; o < 16; o <<= 1) dpriv += __shfl_xor(dpriv, o);
    float inv = 1.f / (dpriv + 1e-16f);
    // bias for stored positions lane*4+{0..3} = actual 64*(lane>>4)+(lane&15)+{0,16,32,48}
    int bbase = ((lane >> 4) << 6) | (lane & 15);
    float b0 = bias[bbase], b1 = bias[bbase + 16], b2 = bias[bbase + 32], b3 = bias[bbase + 48];
    float o0 = a0 * inv + b0;
    float o1 = a1 * inv + b1;
    float o2 = a2 * inv + b2;
    float o3 = a3 * inv + b3;
    if (apply_elu) {
        o0 = o0 > 0.f ? o0 : __expf(o0) - 1.f;
        o1 = o1 > 0.f ? o1 : __expf(o1) - 1.f;
        o2 = o2 > 0.f ? o2 : __expf(o2) - 1.f;
        o3 = o3 > 0.f ? o3 : __expf(o3) - 1.f;
    }
    ushort4 ov;
    ov.x = f2b(o0); ov.y = f2b(o1); ov.z = f2b(o2); ov.w = f2b(o3);
    *(ushort4*)(out + (size_t)dst * HC + lane * 4) = ov;
}

// ---------------- sliced mean-pool partials: block = (graph, 8 node-slices). ----

__global__ __launch_bounds__(256) void pool_kernel(const u16* __restrict__ hin,
                                                   const int* __restrict__ batch,
                                                   float* __restrict__ pp) {
    int g = blockIdx.x;
    int slice = blockIdx.y;            // 0..7
    int lane = threadIdx.x & 63;
    int wid = threadIdx.x >> 6;
    int s = lbound(batch, g), e = lbound(batch, g + 1);
    float a0 = 0.f, a1 = 0.f, a2 = 0.f, a3 = 0.f;
    for (int n = s + slice * 4 + wid; n < e; n += 32) {
        ushort4 hv = *(const ushort4*)(hin + (size_t)n * HC + lane * 4);
        a0 += b2f(hv.x); a1 += b2f(hv.y); a2 += b2f(hv.z); a3 += b2f(hv.w);
    }
    __shared__ float4 part[4][64];
    part[wid][lane] = make_float4(a0, a1, a2, a3);
    __syncthreads();
    if (wid == 0) {
        float4 p0 = part[0][lane], p1 = part[1][lane], p2 = part[2][lane], p3 = part[3][lane];
        float4 v = make_float4((p0.x + p1.x) + (p2.x + p3.x),
                               (p0.y + p1.y) + (p2.y + p3.y),
                               (p0.z + p1.z) + (p2.z + p3.z),
                               (p0.w + p1.w) + (p2.w + p3.w));
        *(float4*)(pp + ((size_t)(g * 8 + slice)) * HC + lane * 4) = v;
    }
}

// ---------------- final classifier: sum 8 slice-partials, mean, Wl dot ----------------

__global__ __launch_bounds__(64) void final_kernel(const float* __restrict__ pp,
                                                   const int* __restrict__ batch,
                                                   const float* __restrict__ Wl,
                                                   const float* __restrict__ bl,
                                                   float* __restrict__ out) {
    int g = blockIdx.x;
    int lane = threadIdx.x;
    float4 pv = make_float4(0.f, 0.f, 0.f, 0.f);
    #pragma unroll
    for (int sl = 0; sl < 8; ++sl) {
        float4 v = *(const float4*)(pp + ((size_t)(g * 8 + sl)) * HC + lane * 4);
        pv.x += v.x; pv.y += v.y; pv.z += v.z; pv.w += v.w;
    }
    int cs = lbound(batch, g), ce = lbound(batch, g + 1);
    float cntf = fmaxf((float)(ce - cs), 1.f);
    float inv = 1.f / cntf;
    pv.x *= inv; pv.y *= inv; pv.z *= inv; pv.w *= inv;
    int wbase = ((lane >> 4) << 6) | (lane & 15);             // actual ch = wbase+{0,16,32,48}
    float acc[NOUT];
    #pragma unroll
    for (int o = 0; o < NOUT; ++o) {
        const float* w = Wl + o * HC + wbase;
        acc[o] = pv.x * w[0] + pv.y * w[16] + pv.z * w[32] + pv.w * w[48];
    }
    #pragma unroll
    for (int s = 32; s > 0; s >>= 1)
        #pragma unroll
        for (int o = 0; o < NOUT; ++o)
            acc[o] += __shfl_xor(acc[o], s);
    if (lane == 0) {
        #pragma unroll
        for (int o = 0; o < NOUT; ++o)
            out[g * NOUT + o] = acc[o] + bl[o];
    }
}

// ---------------- launch ----------------

extern "C" void kernel_launch(void* const* d_in, const int* in_sizes, int n_in,
                              void* d_out, int out_size, void* d_ws, size_t ws_size,
                              hipStream_t stream) {
    (void)in_sizes; (void)n_in; (void)out_size; (void)ws_size;
    const float* x   = (const float*)d_in[0];
    const int*   ei  = (const int*)d_in[1];
    const int*   bat = (const int*)d_in[2];
    const float* W1  = (const float*)d_in[3];
    const float* as1 = (const float*)d_in[4];
    const float* ad1 = (const float*)d_in[5];
    const float* b1  = (const float*)d_in[6];
    const float* W2  = (const float*)d_in[7];
    const float* as2 = (const float*)d_in[8];
    const float* ad2 = (const float*)d_in[9];
    const float* b2  = (const float*)d_in[10];
    const float* W3  = (const float*)d_in[11];
    const float* as3 = (const float*)d_in[12];
    const float* ad3 = (const float*)d_in[13];
    const float* b3  = (const float*)d_in[14];
    const float* Wl  = (const float*)d_in[15];
    const float* bl  = (const float*)d_in[16];
    float* out = (float*)d_out;

    char* ws = (char*)d_ws;
    size_t p = 0;
    auto alloc = [&](size_t bytes) {
        size_t a = p;
        p += (bytes + 255) & ~(size_t)255;
        return a;
    };
    int*      off  = (int*)(ws + alloc((size_t)(NB196 * 256 + 256) * 4));
    int*      bcur = (int*)(ws + alloc(256 * 4));
    int*      ssrc = (int*)(ws + alloc((size_t)ETOT * 4));
    unsigned* tmp  = (unsigned*)(ws + alloc((size_t)NB196 * BCAP * 4));
    float*    es   = (float*)(ws + alloc((size_t)NNODES * NHEAD * 4));
    float*    ed   = (float*)(ws + alloc((size_t)NNODES * NHEAD * 4));
    u16*      xb   = (u16*)(ws + alloc((size_t)NNODES * FIN * 2));
    u16*      w1b  = (u16*)(ws + alloc((size_t)HC * FIN * 2));
    u16*      w2b  = (u16*)(ws + alloc((size_t)HC * HC * 2));
    u16*      w3b  = (u16*)(ws + alloc((size_t)HC * HC * 2));
    u8*       Hb   = (u8*)(ws + alloc((size_t)NNODES * HC));       // fp8 e4m3, σ-layout
    u16*      Ab   = (u16*)(ws + alloc((size_t)NNODES * HC * 2));  // bf16, σ-layout
    float*    pp   = (float*)(ws + alloc((size_t)NGRAPH * 8 * HC * 4));   // pool partials
    alloc(128 * 1024);   // slack: gemm A-tile over-read past row NNODES stays in d_ws

    // zero only the 196 bucket counters
    hipMemsetAsync(bcur, 0, 256 * 4, stream);

    // conversions + edge-sort pass 1 (fused, disjoint block ranges)
    prep_kernel<<<NBCONV + NBS1, 256, 0, stream>>>(x, W1, W2, W3, xb, w1b, w2b, w3b,
                                                   ei, bcur, tmp);
    // edge-sort pass 2 (self-computes global prefix; writes global CSR off[])
    scatter2_kernel<<<NB196, 256, 0, stream>>>(tmp, bcur, off, ssrc);

    dim3 ggrid((NNODES + TBM - 1) / TBM, HC / TBN);
    int nblocks4 = (NNODES + 3) / 4;   // 4 dst per block (1 per wave)

    // layer 1
    gemm_mfma<<<ggrid, 256, 0, stream>>>(xb, w1b, Hb, FIN, as1, ad1, es, ed);
    aggregate_kernel<<<nblocks4, 256, 0, stream>>>(Hb, ssrc, off, es, ed, b1, Ab, 1);
    // layer 2
    gemm_mfma<<<ggrid, 256, 0, stream>>>(Ab, w2b, Hb, HC, as2, ad2, es, ed);
    aggregate_kernel<<<nblocks4, 256, 0, stream>>>(Hb, ssrc, off, es, ed, b2, Ab, 1);
    // layer 3
    gemm_mfma<<<ggrid, 256, 0, stream>>>(Ab, w3b, Hb, HC, as3, ad3, es, ed);
    aggregate_kernel<<<nblocks4, 256, 0, stream>>>(Hb, ssrc, off, es, ed, b3, Ab, 0);

    // pool + classify
    dim3 pgrid(NGRAPH, 8);
    pool_kernel<<<pgrid, 256, 0, stream>>>(Ab, bat, pp);
    final_kernel<<<NGRAPH, 64, 0, stream>>>(pp, bat, Wl, bl, out);
}